// Round 6
// baseline (215.004 us; speedup 1.0000x reference)
//
#include <hip/hip_runtime.h>
#include <stdint.h>

// Causal self-attention: x[8,2048,256] fp32, W_attn[768,256], W_proj[256,256]
// cvt->bf16 (fused), QKV GEMM (K pre-scaled, V transposed), flash attn:
// 32x32x16 MFMA, swapped QK, in-register softmax (R4 lean body),
// 2-way split-K with LDS combine (R5 geometry). proj GEMM.

#define BB 8
#define SS 2048
#define CC 256
#define HH 4
#define DD 64

typedef __attribute__((ext_vector_type(8))) __bf16 bf16x8;
typedef __attribute__((ext_vector_type(4))) __bf16 bf16x4;
typedef __attribute__((ext_vector_type(4))) float f32x4;
typedef __attribute__((ext_vector_type(16))) float f32x16;

#define CM 0.18033688011112042f   // (1/sqrt(64)) * log2(e), folded into K

static __device__ __forceinline__ uint32_t cvtpk(float lo, float hi) {
  uint32_t r;
  asm("v_cvt_pk_bf16_f32 %0, %1, %2" : "=v"(r) : "v"(lo), "v"(hi));
  return r;
}
static __device__ __forceinline__ void pl32swap(uint32_t& a, uint32_t& b) {
  asm("v_permlane32_swap_b32 %0, %1" : "+v"(a), "+v"(b));
}
union PU { uint32_t u[4]; bf16x8 v; };

// ---------------- fused fp32 -> bf16 convert (x, W_attn, W_proj) ------------
__global__ __launch_bounds__(256) void cvt3_kernel(const float* __restrict__ x,
                                                   const float* __restrict__ wa,
                                                   const float* __restrict__ wp,
                                                   __bf16* __restrict__ xb,
                                                   __bf16* __restrict__ wab,
                                                   __bf16* __restrict__ wpb) {
  int i = blockIdx.x * blockDim.x + threadIdx.x;
  const float* in; __bf16* out;
  if (i < 1048576) { in = x; out = xb; }
  else if (i < 1048576 + 49152) { i -= 1048576; in = wa; out = wab; }
  else { i -= 1048576 + 49152; in = wp; out = wpb; }
  float4 v = ((const float4*)in)[i];
  bf16x4 o = { (__bf16)v.x, (__bf16)v.y, (__bf16)v.z, (__bf16)v.w };
  *(bf16x4*)(out + 4 * i) = o;
}

// ---------------- QKV GEMM: qkv = x @ W_attn^T (R4 shape) ----------------
__global__ __launch_bounds__(256) void qkv_gemm(const __bf16* __restrict__ xb,
                                                const __bf16* __restrict__ wb,
                                                __bf16* __restrict__ qb,
                                                __bf16* __restrict__ kb,
                                                __bf16* __restrict__ vtb) {
  const int lane = threadIdx.x & 63;
  const int ln = lane & 15, kg = lane >> 4;
  const int w = threadIdx.x >> 6;
  const int otile = blockIdx.x % 12;
  const int r0 = (blockIdx.x / 12) * 256 + w * 64;
  const int o0 = otile * 64;

  f32x4 acc[4][4] = {};
  for (int c0 = 0; c0 < CC; c0 += 32) {
    bf16x8 a[4], wv[4];
#pragma unroll
    for (int i = 0; i < 4; ++i)
      a[i] = *(const bf16x8*)(xb + (r0 + i * 16 + ln) * CC + c0 + kg * 8);
#pragma unroll
    for (int t = 0; t < 4; ++t)
      wv[t] = *(const bf16x8*)(wb + (o0 + t * 16 + ln) * CC + c0 + kg * 8);
#pragma unroll
    for (int i = 0; i < 4; ++i)
#pragma unroll
      for (int t = 0; t < 4; ++t)
        acc[i][t] = __builtin_amdgcn_mfma_f32_16x16x32_bf16(a[i], wv[t], acc[i][t], 0, 0, 0);
  }
#pragma unroll
  for (int i = 0; i < 4; ++i)
#pragma unroll
    for (int t = 0; t < 4; ++t) {
      int o = o0 + t * 16 + ln;
      int sel = o >> 8;         // 0=q 1=k 2=v
      int oo = o & 255;
      int h = oo >> 6, d = oo & 63;
#pragma unroll
      for (int r = 0; r < 4; ++r) {
        int rout = r0 + i * 16 + kg * 4 + r;
        int b = rout >> 11, s = rout & 2047;
        if (sel == 0)      qb[((b * HH + h) * SS + s) * DD + d] = (__bf16)acc[i][t][r];
        else if (sel == 1) kb[((b * HH + h) * SS + s) * DD + d] = (__bf16)(acc[i][t][r] * CM);
        else               vtb[((b * HH + h) * DD + d) * SS + s] = (__bf16)acc[i][t][r];
      }
    }
}

// ---------------- Flash attention ----------------
// 2048 blocks x 2 waves. Block owns one 32-q chunk; waves split the key range
// into contiguous halves (partials merged via LDS). R4 lean per-tile body.
__global__ __launch_bounds__(128, 4) void attn_kernel(const __bf16* __restrict__ qb,
                                                      const __bf16* __restrict__ kb,
                                                      const __bf16* __restrict__ vtb,
                                                      __bf16* __restrict__ yb) {
  __shared__ float lm[2][32];
  __shared__ float lacc[64][33];
  const int lane = threadIdx.x & 63;
  const int l31 = lane & 31;
  const int hi = lane >> 5;
  const int w = threadIdx.x >> 6;      // 0 or 1

  const int bid = blockIdx.x;
  const int xs = bid & 7;              // XCD slot
  const int j = bid >> 3;              // 0..255
  const int bh = xs + 8 * (j & 3);     // 4 bh per XCD -> 4MB KV in L2
  const int c = 63 - (j >> 2);         // longest chunks first
  const int q0w = c * 32;
  const int q = q0w + l31;

  const __bf16* Q = qb + bh * SS * DD;
  const __bf16* K = kb + bh * SS * DD;
  const __bf16* VT = vtb + bh * DD * SS;

  bf16x8 qf[4];
  {
    const __bf16* Qp = Q + q * DD + hi * 8;
#pragma unroll
    for (int s = 0; s < 4; ++s) qf[s] = *(const bf16x8*)(Qp + s * 16);
  }

  const int ntot = (q0w + 95) >> 6;    // 64-key tiles; last = diagonal
  const int seg = (ntot + 1) >> 1;
  const int kt0 = w * seg;
  const int kt1 = min(kt0 + seg, ntot);
  const int qrel = l31 + 32 * (c & 1);

  f32x16 acc0 = {}, acc1 = {};
  float mrun = -1e30f, lrun = 0.0f;

  if (kt0 < kt1) {
    // K fragments for first tile (A-operand rows = keys)
    bf16x8 ka[2][4];
    {
      const __bf16* Kp = K + (kt0 * 64 + l31) * DD + hi * 8;
#pragma unroll
      for (int s = 0; s < 4; ++s) {
        ka[0][s] = *(const bf16x8*)(Kp + s * 16);
        ka[1][s] = *(const bf16x8*)(Kp + 32 * DD + s * 16);
      }
    }

    for (int kt = kt0; kt < kt1; ++kt) {
      const int kbase = kt * 64;
      // V loads (A-operand: rows = d); needed after softmax
      bf16x8 vf0[4], vf1[4];
      {
        const __bf16* Vp = VT + l31 * SS + kbase + hi * 8;
#pragma unroll
        for (int s = 0; s < 4; ++s) {
          vf0[s] = *(const bf16x8*)(Vp + s * 16);
          vf1[s] = *(const bf16x8*)(Vp + 32 * SS + s * 16);
        }
      }

      // QK^T (swapped): s0 = keys kbase..+31, s1 = +32..63; cols = q
      f32x16 s0 = {}, s1 = {};
      __builtin_amdgcn_s_setprio(1);
#pragma unroll
      for (int s = 0; s < 4; ++s) s0 = __builtin_amdgcn_mfma_f32_32x32x16_bf16(ka[0][s], qf[s], s0, 0, 0, 0);
#pragma unroll
      for (int s = 0; s < 4; ++s) s1 = __builtin_amdgcn_mfma_f32_32x32x16_bf16(ka[1][s], qf[s], s1, 0, 0, 0);
      __builtin_amdgcn_s_setprio(0);

      // prefetch next K tile
      {
        const int pb = (kt + 1 < kt1) ? (kbase + 64) : kbase;
        const __bf16* Kn = K + (pb + l31) * DD + hi * 8;
#pragma unroll
        for (int s = 0; s < 4; ++s) {
          ka[0][s] = *(const bf16x8*)(Kn + s * 16);
          ka[1][s] = *(const bf16x8*)(Kn + 32 * DD + s * 16);
        }
      }

      float p[32];
#pragma unroll
      for (int r = 0; r < 16; ++r) { p[r] = s0[r]; p[16 + r] = s1[r]; }
      if (kt == ntot - 1) {               // diagonal tile: per-lane causal mask
#pragma unroll
        for (int r = 0; r < 16; ++r) {
          int crow = (r & 3) + 8 * (r >> 2) + 4 * hi;
          p[r]      = (crow      <= qrel) ? p[r]      : -1e30f;
          p[16 + r] = (crow + 32 <= qrel) ? p[16 + r] : -1e30f;
        }
      }

      // row max (tree) + cross-half
      float mx[16];
#pragma unroll
      for (int r = 0; r < 16; ++r) mx[r] = fmaxf(p[r], p[16 + r]);
#pragma unroll
      for (int st = 8; st > 0; st >>= 1)
#pragma unroll
        for (int r = 0; r < 8; ++r) if (r < st) mx[r] = fmaxf(mx[r], mx[r + st]);
      float tmax = fmaxf(mx[0], __shfl_xor(mx[0], 32));

      if (!__all(tmax <= mrun)) {         // exact defer: rescale only on new max
        float mnew = fmaxf(mrun, tmax);
        float al = __builtin_amdgcn_exp2f(mrun - mnew);
        mrun = mnew;
        lrun *= al;
        acc0 *= al;
        acc1 *= al;
      }
#pragma unroll
      for (int r = 0; r < 32; ++r) p[r] = __builtin_amdgcn_exp2f(p[r] - mrun);

      // row sum (tree) + cross-half
      float sm[16];
#pragma unroll
      for (int r = 0; r < 16; ++r) sm[r] = p[r] + p[16 + r];
#pragma unroll
      for (int st = 8; st > 0; st >>= 1)
#pragma unroll
        for (int r = 0; r < 8; ++r) if (r < st) sm[r] += sm[r + st];
      lrun += sm[0] + __shfl_xor(sm[0], 32);

      // repack P -> B-fragments: cvt_pk + permlane32_swap (no LDS)
      bf16x8 pf[4];
#pragma unroll
      for (int g = 0; g < 4; ++g) {
        const int o = (g >> 1) * 16 + (g & 1) * 8;
        uint32_t a = cvtpk(p[o + 0], p[o + 1]);
        uint32_t b = cvtpk(p[o + 4], p[o + 5]);
        uint32_t c2 = cvtpk(p[o + 2], p[o + 3]);
        uint32_t d2 = cvtpk(p[o + 6], p[o + 7]);
        pl32swap(a, b);
        pl32swap(c2, d2);
        PU u; u.u[0] = a; u.u[1] = c2; u.u[2] = b; u.u[3] = d2;
        pf[g] = u.v;
      }

      // PV: acc[dg] += V^T[dg] . P
      __builtin_amdgcn_s_setprio(1);
#pragma unroll
      for (int g = 0; g < 4; ++g) acc0 = __builtin_amdgcn_mfma_f32_32x32x16_bf16(vf0[g], pf[g], acc0, 0, 0, 0);
#pragma unroll
      for (int g = 0; g < 4; ++g) acc1 = __builtin_amdgcn_mfma_f32_32x32x16_bf16(vf1[g], pf[g], acc1, 0, 0, 0);
      __builtin_amdgcn_s_setprio(0);
    }
  }

  // ---- split-K combine: wave1 -> LDS, wave0 merges + writes y ----
  if (w == 1) {
    if (hi == 0) { lm[0][l31] = mrun; lm[1][l31] = lrun; }
#pragma unroll
    for (int r = 0; r < 16; ++r) {
      int d0 = (r & 3) + 8 * (r >> 2) + 4 * hi;
      lacc[d0][l31] = acc0[r];
      lacc[32 + d0][l31] = acc1[r];
    }
  }
  __syncthreads();
  if (w == 0) {
    float m1 = lm[0][l31], l1 = lm[1][l31];
    float M = fmaxf(mrun, m1);
    float f0 = __builtin_amdgcn_exp2f(mrun - M);
    float f1 = __builtin_amdgcn_exp2f(m1 - M);
    float L = lrun * f0 + l1 * f1;
    float inv = __builtin_amdgcn_rcpf(L);
    const int b = bh >> 2, h = bh & 3;
    __bf16* yrow = yb + (b * SS + q) * CC + h * DD;
#pragma unroll
    for (int g = 0; g < 4; ++g) {
      float a0[4], a1[4];
#pragma unroll
      for (int i2 = 0; i2 < 4; ++i2) {
        int d0 = i2 + 8 * g + 4 * hi;
        a0[i2] = (acc0[g * 4 + i2] * f0 + lacc[d0][l31] * f1) * inv;
        a1[i2] = (acc1[g * 4 + i2] * f0 + lacc[32 + d0][l31] * f1) * inv;
      }
      uint32_t w0 = cvtpk(a0[0], a0[1]);
      uint32_t w1 = cvtpk(a0[2], a0[3]);
      uint2 st0 = { w0, w1 };
      *(uint2*)(yrow + g * 8 + hi * 4) = st0;
      w0 = cvtpk(a1[0], a1[1]);
      w1 = cvtpk(a1[2], a1[3]);
      uint2 st1 = { w0, w1 };
      *(uint2*)(yrow + 32 + g * 8 + hi * 4) = st1;
    }
  }
}

// ---------------- Proj GEMM: out = y @ W_proj^T (fp32 out, R4 shape) --------
__global__ __launch_bounds__(256) void proj_gemm(const __bf16* __restrict__ yb,
                                                 const __bf16* __restrict__ wpb,
                                                 float* __restrict__ out) {
  const int lane = threadIdx.x & 63;
  const int ln = lane & 15, kg = lane >> 4;
  const int w = threadIdx.x >> 6;
  const int otile = blockIdx.x & 3;
  const int r0 = (blockIdx.x >> 2) * 256 + w * 64;
  const int o0 = otile * 64;

  f32x4 acc[4][4] = {};
  for (int c0 = 0; c0 < CC; c0 += 32) {
    bf16x8 a[4], wv[4];
#pragma unroll
    for (int i = 0; i < 4; ++i)
      a[i] = *(const bf16x8*)(yb + (r0 + i * 16 + ln) * CC + c0 + kg * 8);
#pragma unroll
    for (int t = 0; t < 4; ++t)
      wv[t] = *(const bf16x8*)(wpb + (o0 + t * 16 + ln) * CC + c0 + kg * 8);
#pragma unroll
    for (int i = 0; i < 4; ++i)
#pragma unroll
      for (int t = 0; t < 4; ++t)
        acc[i][t] = __builtin_amdgcn_mfma_f32_16x16x32_bf16(a[i], wv[t], acc[i][t], 0, 0, 0);
  }
#pragma unroll
  for (int i = 0; i < 4; ++i)
#pragma unroll
    for (int t = 0; t < 4; ++t) {
      int o = o0 + t * 16 + ln;
#pragma unroll
      for (int r = 0; r < 4; ++r) {
        int rout = r0 + i * 16 + kg * 4 + r;
        out[rout * 256 + o] = acc[i][t][r];
      }
    }
}

extern "C" void kernel_launch(void* const* d_in, const int* in_sizes, int n_in,
                              void* d_out, int out_size, void* d_ws, size_t ws_size,
                              hipStream_t stream) {
  const float* x = (const float*)d_in[0];
  const float* Wa = (const float*)d_in[1];
  const float* Wp = (const float*)d_in[2];

  char* ws = (char*)d_ws;
  __bf16* xb  = (__bf16*)(ws);                    // 8 MiB  [B*S][C]
  __bf16* qb  = (__bf16*)(ws + 8388608);          // 8 MiB  [BH][S][D]
  __bf16* kb  = (__bf16*)(ws + 16777216);         // 8 MiB  [BH][S][D] (pre-scaled)
  __bf16* vtb = (__bf16*)(ws + 25165824);         // 8 MiB  [BH][D][S]
  __bf16* yb  = (__bf16*)(ws + 33554432);         // 8 MiB  [B,S,C]
  __bf16* wab = (__bf16*)(ws + 41943040);         // 384 KiB [768][256]
  __bf16* wpb = (__bf16*)(ws + 42336256);         // 128 KiB [256][256]

  cvt3_kernel<<<4352, 256, 0, stream>>>(x, Wa, Wp, xb, wab, wpb);
  qkv_gemm<<<768, 256, 0, stream>>>(xb, wab, qb, kb, vtb);
  attn_kernel<<<2048, 128, 0, stream>>>(qb, kb, vtb, yb);
  proj_gemm<<<256, 256, 0, stream>>>(yb, wpb, (float*)d_out);
}

// Round 7
// 134.130 us; speedup vs baseline: 1.6030x; 1.6030x over previous
//
#include <hip/hip_runtime.h>
#include <stdint.h>

// Causal self-attention: x[8,2048,256] fp32, W_attn[768,256], W_proj[256,256]
// cvt->bf16 (fused), QKV GEMM (K pre-scaled, V transposed), flash attn:
// 32x32x16 MFMA, swapped QK, in-register softmax (lean body),
// 2-way split-K with LDS combine. proj GEMM.

#define BB 8
#define SS 2048
#define CC 256
#define HH 4
#define DD 64

typedef __attribute__((ext_vector_type(8))) __bf16 bf16x8;
typedef __attribute__((ext_vector_type(4))) __bf16 bf16x4;
typedef __attribute__((ext_vector_type(4))) float f32x4;
typedef __attribute__((ext_vector_type(16))) float f32x16;

#define CM 0.18033688011112042f   // (1/sqrt(64)) * log2(e), folded into K

static __device__ __forceinline__ uint32_t cvtpk(float lo, float hi) {
  uint32_t r;
  asm("v_cvt_pk_bf16_f32 %0, %1, %2" : "=v"(r) : "v"(lo), "v"(hi));
  return r;
}
static __device__ __forceinline__ void pl32swap(uint32_t& a, uint32_t& b) {
  asm("v_permlane32_swap_b32 %0, %1" : "+v"(a), "+v"(b));
}
union PU { uint32_t u[4]; bf16x8 v; };

// ---------------- fused fp32 -> bf16 convert (x, W_attn, W_proj) ------------
__global__ __launch_bounds__(256) void cvt3_kernel(const float* __restrict__ x,
                                                   const float* __restrict__ wa,
                                                   const float* __restrict__ wp,
                                                   __bf16* __restrict__ xb,
                                                   __bf16* __restrict__ wab,
                                                   __bf16* __restrict__ wpb) {
  int i = blockIdx.x * blockDim.x + threadIdx.x;
  const float* in; __bf16* out;
  if (i < 1048576) { in = x; out = xb; }
  else if (i < 1048576 + 49152) { i -= 1048576; in = wa; out = wab; }
  else { i -= 1048576 + 49152; in = wp; out = wpb; }
  float4 v = ((const float4*)in)[i];
  bf16x4 o = { (__bf16)v.x, (__bf16)v.y, (__bf16)v.z, (__bf16)v.w };
  *(bf16x4*)(out + 4 * i) = o;
}

// ---------------- QKV GEMM: qkv = x @ W_attn^T ----------------
__global__ __launch_bounds__(256) void qkv_gemm(const __bf16* __restrict__ xb,
                                                const __bf16* __restrict__ wb,
                                                __bf16* __restrict__ qb,
                                                __bf16* __restrict__ kb,
                                                __bf16* __restrict__ vtb) {
  const int lane = threadIdx.x & 63;
  const int ln = lane & 15, kg = lane >> 4;
  const int w = threadIdx.x >> 6;
  const int otile = blockIdx.x % 12;
  const int r0 = (blockIdx.x / 12) * 256 + w * 64;
  const int o0 = otile * 64;

  f32x4 acc[4][4] = {};
  for (int c0 = 0; c0 < CC; c0 += 32) {
    bf16x8 a[4], wv[4];
#pragma unroll
    for (int i = 0; i < 4; ++i)
      a[i] = *(const bf16x8*)(xb + (r0 + i * 16 + ln) * CC + c0 + kg * 8);
#pragma unroll
    for (int t = 0; t < 4; ++t)
      wv[t] = *(const bf16x8*)(wb + (o0 + t * 16 + ln) * CC + c0 + kg * 8);
#pragma unroll
    for (int i = 0; i < 4; ++i)
#pragma unroll
      for (int t = 0; t < 4; ++t)
        acc[i][t] = __builtin_amdgcn_mfma_f32_16x16x32_bf16(a[i], wv[t], acc[i][t], 0, 0, 0);
  }
#pragma unroll
  for (int i = 0; i < 4; ++i)
#pragma unroll
    for (int t = 0; t < 4; ++t) {
      int o = o0 + t * 16 + ln;
      int sel = o >> 8;         // 0=q 1=k 2=v
      int oo = o & 255;
      int h = oo >> 6, d = oo & 63;
#pragma unroll
      for (int r = 0; r < 4; ++r) {
        int rout = r0 + i * 16 + kg * 4 + r;
        int b = rout >> 11, s = rout & 2047;
        if (sel == 0)      qb[((b * HH + h) * SS + s) * DD + d] = (__bf16)acc[i][t][r];
        else if (sel == 1) kb[((b * HH + h) * SS + s) * DD + d] = (__bf16)(acc[i][t][r] * CM);
        else               vtb[((b * HH + h) * DD + d) * SS + s] = (__bf16)acc[i][t][r];
      }
    }
}

// ---------------- Flash attention ----------------
// 2048 blocks x 2 waves. Block owns one 32-q chunk; waves split the key range
// into contiguous halves (partials merged via LDS). Lean per-tile body.
// launch_bounds(128,3): reg cap ~170/wave >= ~156 needed -> no spill, 3 waves/EU.
__global__ __launch_bounds__(128, 3) void attn_kernel(const __bf16* __restrict__ qb,
                                                      const __bf16* __restrict__ kb,
                                                      const __bf16* __restrict__ vtb,
                                                      __bf16* __restrict__ yb) {
  __shared__ float lm[2][32];
  __shared__ float lacc[64][33];
  const int lane = threadIdx.x & 63;
  const int l31 = lane & 31;
  const int hi = lane >> 5;
  const int w = threadIdx.x >> 6;      // 0 or 1

  const int bid = blockIdx.x;
  const int xs = bid & 7;              // XCD slot
  const int j = bid >> 3;              // 0..255
  const int bh = xs + 8 * (j & 3);     // 4 bh per XCD -> 4MB KV in L2
  const int c = 63 - (j >> 2);         // longest chunks first
  const int q0w = c * 32;
  const int q = q0w + l31;

  const __bf16* Q = qb + bh * SS * DD;
  const __bf16* K = kb + bh * SS * DD;
  const __bf16* VT = vtb + bh * DD * SS;

  bf16x8 qf[4];
  {
    const __bf16* Qp = Q + q * DD + hi * 8;
#pragma unroll
    for (int s = 0; s < 4; ++s) qf[s] = *(const bf16x8*)(Qp + s * 16);
  }

  const int ntot = (q0w + 95) >> 6;    // 64-key tiles; last = diagonal
  const int seg = (ntot + 1) >> 1;
  const int kt0 = w * seg;
  const int kt1 = min(kt0 + seg, ntot);
  const int qrel = l31 + 32 * (c & 1);

  f32x16 acc0 = {}, acc1 = {};
  float mrun = -1e30f, lrun = 0.0f;

  if (kt0 < kt1) {
    // K fragments for first tile (A-operand rows = keys)
    bf16x8 ka[2][4];
    {
      const __bf16* Kp = K + (kt0 * 64 + l31) * DD + hi * 8;
#pragma unroll
      for (int s = 0; s < 4; ++s) {
        ka[0][s] = *(const bf16x8*)(Kp + s * 16);
        ka[1][s] = *(const bf16x8*)(Kp + 32 * DD + s * 16);
      }
    }

    for (int kt = kt0; kt < kt1; ++kt) {
      const int kbase = kt * 64;
      // V loads (A-operand: rows = d); needed after softmax
      bf16x8 vf0[4], vf1[4];
      {
        const __bf16* Vp = VT + l31 * SS + kbase + hi * 8;
#pragma unroll
        for (int s = 0; s < 4; ++s) {
          vf0[s] = *(const bf16x8*)(Vp + s * 16);
          vf1[s] = *(const bf16x8*)(Vp + 32 * SS + s * 16);
        }
      }

      // QK^T (swapped): s0 = keys kbase..+31, s1 = +32..63; cols = q
      f32x16 s0 = {}, s1 = {};
      __builtin_amdgcn_s_setprio(1);
#pragma unroll
      for (int s = 0; s < 4; ++s) s0 = __builtin_amdgcn_mfma_f32_32x32x16_bf16(ka[0][s], qf[s], s0, 0, 0, 0);
#pragma unroll
      for (int s = 0; s < 4; ++s) s1 = __builtin_amdgcn_mfma_f32_32x32x16_bf16(ka[1][s], qf[s], s1, 0, 0, 0);
      __builtin_amdgcn_s_setprio(0);

      // prefetch next K tile
      {
        const int pb = (kt + 1 < kt1) ? (kbase + 64) : kbase;
        const __bf16* Kn = K + (pb + l31) * DD + hi * 8;
#pragma unroll
        for (int s = 0; s < 4; ++s) {
          ka[0][s] = *(const bf16x8*)(Kn + s * 16);
          ka[1][s] = *(const bf16x8*)(Kn + 32 * DD + s * 16);
        }
      }

      float p[32];
#pragma unroll
      for (int r = 0; r < 16; ++r) { p[r] = s0[r]; p[16 + r] = s1[r]; }
      if (kt == ntot - 1) {               // diagonal tile: per-lane causal mask
#pragma unroll
        for (int r = 0; r < 16; ++r) {
          int crow = (r & 3) + 8 * (r >> 2) + 4 * hi;
          p[r]      = (crow      <= qrel) ? p[r]      : -1e30f;
          p[16 + r] = (crow + 32 <= qrel) ? p[16 + r] : -1e30f;
        }
      }

      // row max (tree) + cross-half
      float mx[16];
#pragma unroll
      for (int r = 0; r < 16; ++r) mx[r] = fmaxf(p[r], p[16 + r]);
#pragma unroll
      for (int st = 8; st > 0; st >>= 1)
#pragma unroll
        for (int r = 0; r < 8; ++r) if (r < st) mx[r] = fmaxf(mx[r], mx[r + st]);
      float tmax = fmaxf(mx[0], __shfl_xor(mx[0], 32));

      if (!__all(tmax <= mrun)) {         // exact defer: rescale only on new max
        float mnew = fmaxf(mrun, tmax);
        float al = __builtin_amdgcn_exp2f(mrun - mnew);
        mrun = mnew;
        lrun *= al;
        acc0 *= al;
        acc1 *= al;
      }
#pragma unroll
      for (int r = 0; r < 32; ++r) p[r] = __builtin_amdgcn_exp2f(p[r] - mrun);

      // row sum (tree) + cross-half
      float sm[16];
#pragma unroll
      for (int r = 0; r < 16; ++r) sm[r] = p[r] + p[16 + r];
#pragma unroll
      for (int st = 8; st > 0; st >>= 1)
#pragma unroll
        for (int r = 0; r < 8; ++r) if (r < st) sm[r] += sm[r + st];
      lrun += sm[0] + __shfl_xor(sm[0], 32);

      // repack P -> B-fragments: cvt_pk + permlane32_swap (no LDS)
      bf16x8 pf[4];
#pragma unroll
      for (int g = 0; g < 4; ++g) {
        const int o = (g >> 1) * 16 + (g & 1) * 8;
        uint32_t a = cvtpk(p[o + 0], p[o + 1]);
        uint32_t b = cvtpk(p[o + 4], p[o + 5]);
        uint32_t c2 = cvtpk(p[o + 2], p[o + 3]);
        uint32_t d2 = cvtpk(p[o + 6], p[o + 7]);
        pl32swap(a, b);
        pl32swap(c2, d2);
        PU u; u.u[0] = a; u.u[1] = c2; u.u[2] = b; u.u[3] = d2;
        pf[g] = u.v;
      }

      // PV: acc[dg] += V^T[dg] . P
      __builtin_amdgcn_s_setprio(1);
#pragma unroll
      for (int g = 0; g < 4; ++g) acc0 = __builtin_amdgcn_mfma_f32_32x32x16_bf16(vf0[g], pf[g], acc0, 0, 0, 0);
#pragma unroll
      for (int g = 0; g < 4; ++g) acc1 = __builtin_amdgcn_mfma_f32_32x32x16_bf16(vf1[g], pf[g], acc1, 0, 0, 0);
      __builtin_amdgcn_s_setprio(0);
    }
  }

  // ---- split-K combine: wave1 -> LDS, wave0 merges + writes y ----
  if (w == 1) {
    if (hi == 0) { lm[0][l31] = mrun; lm[1][l31] = lrun; }
#pragma unroll
    for (int r = 0; r < 16; ++r) {
      int d0 = (r & 3) + 8 * (r >> 2) + 4 * hi;
      lacc[d0][l31] = acc0[r];
      lacc[32 + d0][l31] = acc1[r];
    }
  }
  __syncthreads();
  if (w == 0) {
    float m1 = lm[0][l31], l1 = lm[1][l31];
    float M = fmaxf(mrun, m1);
    float f0 = __builtin_amdgcn_exp2f(mrun - M);
    float f1 = __builtin_amdgcn_exp2f(m1 - M);
    float L = lrun * f0 + l1 * f1;
    float inv = __builtin_amdgcn_rcpf(L);
    const int b = bh >> 2, h = bh & 3;
    __bf16* yrow = yb + (b * SS + q) * CC + h * DD;
#pragma unroll
    for (int g = 0; g < 4; ++g) {
      float a0[4], a1[4];
#pragma unroll
      for (int i2 = 0; i2 < 4; ++i2) {
        int d0 = i2 + 8 * g + 4 * hi;
        a0[i2] = (acc0[g * 4 + i2] * f0 + lacc[d0][l31] * f1) * inv;
        a1[i2] = (acc1[g * 4 + i2] * f0 + lacc[32 + d0][l31] * f1) * inv;
      }
      uint32_t w0 = cvtpk(a0[0], a0[1]);
      uint32_t w1 = cvtpk(a0[2], a0[3]);
      uint2 st0 = { w0, w1 };
      *(uint2*)(yrow + g * 8 + hi * 4) = st0;
      w0 = cvtpk(a1[0], a1[1]);
      w1 = cvtpk(a1[2], a1[3]);
      uint2 st1 = { w0, w1 };
      *(uint2*)(yrow + 32 + g * 8 + hi * 4) = st1;
    }
  }
}

// ---------------- Proj GEMM: out = y @ W_proj^T (fp32 out) ------------------
__global__ __launch_bounds__(256) void proj_gemm(const __bf16* __restrict__ yb,
                                                 const __bf16* __restrict__ wpb,
                                                 float* __restrict__ out) {
  const int lane = threadIdx.x & 63;
  const int ln = lane & 15, kg = lane >> 4;
  const int w = threadIdx.x >> 6;
  const int otile = blockIdx.x & 3;
  const int r0 = (blockIdx.x >> 2) * 256 + w * 64;
  const int o0 = otile * 64;

  f32x4 acc[4][4] = {};
  for (int c0 = 0; c0 < CC; c0 += 32) {
    bf16x8 a[4], wv[4];
#pragma unroll
    for (int i = 0; i < 4; ++i)
      a[i] = *(const bf16x8*)(yb + (r0 + i * 16 + ln) * CC + c0 + kg * 8);
#pragma unroll
    for (int t = 0; t < 4; ++t)
      wv[t] = *(const bf16x8*)(wpb + (o0 + t * 16 + ln) * CC + c0 + kg * 8);
#pragma unroll
    for (int i = 0; i < 4; ++i)
#pragma unroll
      for (int t = 0; t < 4; ++t)
        acc[i][t] = __builtin_amdgcn_mfma_f32_16x16x32_bf16(a[i], wv[t], acc[i][t], 0, 0, 0);
  }
#pragma unroll
  for (int i = 0; i < 4; ++i)
#pragma unroll
    for (int t = 0; t < 4; ++t) {
      int o = o0 + t * 16 + ln;
#pragma unroll
      for (int r = 0; r < 4; ++r) {
        int rout = r0 + i * 16 + kg * 4 + r;
        out[rout * 256 + o] = acc[i][t][r];
      }
    }
}

extern "C" void kernel_launch(void* const* d_in, const int* in_sizes, int n_in,
                              void* d_out, int out_size, void* d_ws, size_t ws_size,
                              hipStream_t stream) {
  const float* x = (const float*)d_in[0];
  const float* Wa = (const float*)d_in[1];
  const float* Wp = (const float*)d_in[2];

  char* ws = (char*)d_ws;
  __bf16* xb  = (__bf16*)(ws);                    // 8 MiB  [B*S][C]
  __bf16* qb  = (__bf16*)(ws + 8388608);          // 8 MiB  [BH][S][D]
  __bf16* kb  = (__bf16*)(ws + 16777216);         // 8 MiB  [BH][S][D] (pre-scaled)
  __bf16* vtb = (__bf16*)(ws + 25165824);         // 8 MiB  [BH][D][S]
  __bf16* yb  = (__bf16*)(ws + 33554432);         // 8 MiB  [B,S,C]
  __bf16* wab = (__bf16*)(ws + 41943040);         // 384 KiB [768][256]
  __bf16* wpb = (__bf16*)(ws + 42336256);         // 128 KiB [256][256]

  cvt3_kernel<<<4352, 256, 0, stream>>>(x, Wa, Wp, xb, wab, wpb);
  qkv_gemm<<<768, 256, 0, stream>>>(xb, wab, qb, kb, vtb);
  attn_kernel<<<2048, 128, 0, stream>>>(qb, kb, vtb, yb);
  proj_gemm<<<256, 256, 0, stream>>>(yb, wpb, (float*)d_out);
}

// Round 8
// 92.824 us; speedup vs baseline: 2.3163x; 1.4450x over previous
//
#include <hip/hip_runtime.h>
#include <stdint.h>

// Causal self-attention: x[8,2048,256] fp32, W_attn[768,256], W_proj[256,256]
// cvt->bf16 (fused), QKV GEMM writing FRAGMENT-CONTIGUOUS Qf/Kf/Vf layouts
// (K pre-scaled by 1/sqrt(D)*log2e), flash attn: 32x32x16 MFMA, swapped QK,
// in-register softmax, 2-way split-K + LDS combine, all loads 1KB-coalesced.
// proj GEMM.
//
// Fragment layouts (per bh, 131072 elems):
//  Qf: [chunk32][sblk=d>>4][q&31][d&15]        off = c*2048 + (d>>4)*512 + (q&31)*16 + (d&15)
//  Kf: [tile64][sblk=d>>4][key&63][d&15]       off = t*4096 + (d>>4)*1024 + (s&63)*16 + (d&15)
//  Vf: [tile64][kblk=(s>>4)&3][d][s&15]        off = t*4096 + ((s>>4)&3)*1024 + d*16 + (s&15)
// Wave load for any fragment: contiguous 1KB, lane offset = l31*16 + hi*8.

#define BB 8
#define SS 2048
#define CC 256
#define HH 4
#define DD 64

typedef __attribute__((ext_vector_type(8))) __bf16 bf16x8;
typedef __attribute__((ext_vector_type(4))) __bf16 bf16x4;
typedef __attribute__((ext_vector_type(4))) float f32x4;
typedef __attribute__((ext_vector_type(16))) float f32x16;

#define CM 0.18033688011112042f   // (1/sqrt(64)) * log2(e), folded into K

static __device__ __forceinline__ uint32_t cvtpk(float lo, float hi) {
  uint32_t r;
  asm("v_cvt_pk_bf16_f32 %0, %1, %2" : "=v"(r) : "v"(lo), "v"(hi));
  return r;
}
static __device__ __forceinline__ void pl32swap(uint32_t& a, uint32_t& b) {
  asm("v_permlane32_swap_b32 %0, %1" : "+v"(a), "+v"(b));
}
union PU { uint32_t u[4]; bf16x8 v; };

// ---------------- fused fp32 -> bf16 convert (x, W_attn, W_proj) ------------
__global__ __launch_bounds__(256) void cvt3_kernel(const float* __restrict__ x,
                                                   const float* __restrict__ wa,
                                                   const float* __restrict__ wp,
                                                   __bf16* __restrict__ xb,
                                                   __bf16* __restrict__ wab,
                                                   __bf16* __restrict__ wpb) {
  int i = blockIdx.x * blockDim.x + threadIdx.x;
  const float* in; __bf16* out;
  if (i < 1048576) { in = x; out = xb; }
  else if (i < 1048576 + 49152) { i -= 1048576; in = wa; out = wab; }
  else { i -= 1048576 + 49152; in = wp; out = wpb; }
  float4 v = ((const float4*)in)[i];
  bf16x4 o = { (__bf16)v.x, (__bf16)v.y, (__bf16)v.z, (__bf16)v.w };
  *(bf16x4*)(out + 4 * i) = o;
}

// ---------------- QKV GEMM: qkv = x @ W_attn^T -> Qf/Kf/Vf ----------------
__global__ __launch_bounds__(256) void qkv_gemm(const __bf16* __restrict__ xb,
                                                const __bf16* __restrict__ wb,
                                                __bf16* __restrict__ qf_,
                                                __bf16* __restrict__ kf_,
                                                __bf16* __restrict__ vf_) {
  const int lane = threadIdx.x & 63;
  const int ln = lane & 15, kg = lane >> 4;
  const int w = threadIdx.x >> 6;
  const int otile = blockIdx.x % 12;
  const int r0 = (blockIdx.x / 12) * 256 + w * 64;
  const int o0 = otile * 64;

  f32x4 acc[4][4] = {};
  for (int c0 = 0; c0 < CC; c0 += 32) {
    bf16x8 a[4], wv[4];
#pragma unroll
    for (int i = 0; i < 4; ++i)
      a[i] = *(const bf16x8*)(xb + (r0 + i * 16 + ln) * CC + c0 + kg * 8);
#pragma unroll
    for (int t = 0; t < 4; ++t)
      wv[t] = *(const bf16x8*)(wb + (o0 + t * 16 + ln) * CC + c0 + kg * 8);
#pragma unroll
    for (int i = 0; i < 4; ++i)
#pragma unroll
      for (int t = 0; t < 4; ++t)
        acc[i][t] = __builtin_amdgcn_mfma_f32_16x16x32_bf16(a[i], wv[t], acc[i][t], 0, 0, 0);
  }
#pragma unroll
  for (int i = 0; i < 4; ++i)
#pragma unroll
    for (int t = 0; t < 4; ++t) {
      int o = o0 + t * 16 + ln;
      int sel = o >> 8;         // 0=q 1=k 2=v
      int oo = o & 255;
      int h = oo >> 6, d = oo & 63;
#pragma unroll
      for (int r = 0; r < 4; ++r) {
        int rout = r0 + i * 16 + kg * 4 + r;
        int b = rout >> 11, s = rout & 2047;
        int bh = (b * HH + h) * 131072;
        if (sel == 0) {
          int off = bh + (s >> 5) * 2048 + (d >> 4) * 512 + (s & 31) * 16 + (d & 15);
          qf_[off] = (__bf16)acc[i][t][r];
        } else if (sel == 1) {
          int off = bh + (s >> 6) * 4096 + (d >> 4) * 1024 + (s & 63) * 16 + (d & 15);
          kf_[off] = (__bf16)(acc[i][t][r] * CM);
        } else {
          int off = bh + (s >> 6) * 4096 + ((s >> 4) & 3) * 1024 + d * 16 + (s & 15);
          vf_[off] = (__bf16)acc[i][t][r];
        }
      }
    }
}

// ---------------- Flash attention ----------------
// 2048 blocks x 2 waves. Block owns one 32-q chunk; waves split the key range
// into contiguous halves (partials merged via LDS). All loads 1KB-coalesced.
__global__ __launch_bounds__(128, 3) void attn_kernel(const __bf16* __restrict__ qf_,
                                                      const __bf16* __restrict__ kf_,
                                                      const __bf16* __restrict__ vf_,
                                                      __bf16* __restrict__ yb) {
  __shared__ float lm[2][32];
  __shared__ float lacc[64][33];
  const int lane = threadIdx.x & 63;
  const int l31 = lane & 31;
  const int hi = lane >> 5;
  const int w = threadIdx.x >> 6;      // 0 or 1

  const int bid = blockIdx.x;
  const int xs = bid & 7;              // XCD slot
  const int j = bid >> 3;              // 0..255
  const int bh = xs + 8 * (j & 3);     // 4 bh per XCD -> 4MB KV in L2
  const int c = 63 - (j >> 2);         // longest chunks first
  const int q0w = c * 32;
  const int q = q0w + l31;

  const int loff = l31 * 16 + hi * 8;  // lane offset within any 1KB fragment

  const __bf16* Qfb = qf_ + bh * 131072 + c * 2048 + loff;
  const __bf16* Kb  = kf_ + bh * 131072 + loff;
  const __bf16* Vb  = vf_ + bh * 131072 + loff;

  bf16x8 qf[4];
#pragma unroll
  for (int s = 0; s < 4; ++s) qf[s] = *(const bf16x8*)(Qfb + s * 512);

  const int ntot = (q0w + 95) >> 6;    // 64-key tiles; last = diagonal
  const int seg = (ntot + 1) >> 1;
  const int kt0 = w * seg;
  const int kt1 = min(kt0 + seg, ntot);
  const int qrel = l31 + 32 * (c & 1);

  f32x16 acc0 = {}, acc1 = {};
  float mrun = -1e30f, lrun = 0.0f;

  if (kt0 < kt1) {
    // K fragments for first tile
    bf16x8 ka[2][4];
    {
      const __bf16* Kp = Kb + kt0 * 4096;
#pragma unroll
      for (int s = 0; s < 4; ++s) {
        ka[0][s] = *(const bf16x8*)(Kp + s * 1024);
        ka[1][s] = *(const bf16x8*)(Kp + s * 1024 + 512);
      }
    }

    for (int kt = kt0; kt < kt1; ++kt) {
      // V loads (coalesced fragment bursts)
      bf16x8 vf0[4], vf1[4];
      {
        const __bf16* Vp = Vb + kt * 4096;
#pragma unroll
        for (int s = 0; s < 4; ++s) {
          vf0[s] = *(const bf16x8*)(Vp + s * 1024);
          vf1[s] = *(const bf16x8*)(Vp + s * 1024 + 512);
        }
      }

      // QK^T (swapped): s0 = keys kbase..+31, s1 = +32..63; cols = q
      f32x16 s0 = {}, s1 = {};
      __builtin_amdgcn_s_setprio(1);
#pragma unroll
      for (int s = 0; s < 4; ++s) s0 = __builtin_amdgcn_mfma_f32_32x32x16_bf16(ka[0][s], qf[s], s0, 0, 0, 0);
#pragma unroll
      for (int s = 0; s < 4; ++s) s1 = __builtin_amdgcn_mfma_f32_32x32x16_bf16(ka[1][s], qf[s], s1, 0, 0, 0);
      __builtin_amdgcn_s_setprio(0);

      // prefetch next K tile
      {
        const int pb = (kt + 1 < kt1) ? (kt + 1) : kt;
        const __bf16* Kn = Kb + pb * 4096;
#pragma unroll
        for (int s = 0; s < 4; ++s) {
          ka[0][s] = *(const bf16x8*)(Kn + s * 1024);
          ka[1][s] = *(const bf16x8*)(Kn + s * 1024 + 512);
        }
      }

      float p[32];
#pragma unroll
      for (int r = 0; r < 16; ++r) { p[r] = s0[r]; p[16 + r] = s1[r]; }
      if (kt == ntot - 1) {               // diagonal tile: per-lane causal mask
#pragma unroll
        for (int r = 0; r < 16; ++r) {
          int crow = (r & 3) + 8 * (r >> 2) + 4 * hi;
          p[r]      = (crow      <= qrel) ? p[r]      : -1e30f;
          p[16 + r] = (crow + 32 <= qrel) ? p[16 + r] : -1e30f;
        }
      }

      // row max (tree) + cross-half
      float mx[16];
#pragma unroll
      for (int r = 0; r < 16; ++r) mx[r] = fmaxf(p[r], p[16 + r]);
#pragma unroll
      for (int st = 8; st > 0; st >>= 1)
#pragma unroll
        for (int r = 0; r < 8; ++r) if (r < st) mx[r] = fmaxf(mx[r], mx[r + st]);
      float tmax = fmaxf(mx[0], __shfl_xor(mx[0], 32));

      if (!__all(tmax <= mrun)) {         // exact defer: rescale only on new max
        float mnew = fmaxf(mrun, tmax);
        float al = __builtin_amdgcn_exp2f(mrun - mnew);
        mrun = mnew;
        lrun *= al;
        acc0 *= al;
        acc1 *= al;
      }
#pragma unroll
      for (int r = 0; r < 32; ++r) p[r] = __builtin_amdgcn_exp2f(p[r] - mrun);

      // row sum (tree) + cross-half
      float sm[16];
#pragma unroll
      for (int r = 0; r < 16; ++r) sm[r] = p[r] + p[16 + r];
#pragma unroll
      for (int st = 8; st > 0; st >>= 1)
#pragma unroll
        for (int r = 0; r < 8; ++r) if (r < st) sm[r] += sm[r + st];
      lrun += sm[0] + __shfl_xor(sm[0], 32);

      // repack P -> B-fragments: cvt_pk + permlane32_swap (no LDS)
      bf16x8 pf[4];
#pragma unroll
      for (int g = 0; g < 4; ++g) {
        const int o = (g >> 1) * 16 + (g & 1) * 8;
        uint32_t a = cvtpk(p[o + 0], p[o + 1]);
        uint32_t b = cvtpk(p[o + 4], p[o + 5]);
        uint32_t c2 = cvtpk(p[o + 2], p[o + 3]);
        uint32_t d2 = cvtpk(p[o + 6], p[o + 7]);
        pl32swap(a, b);
        pl32swap(c2, d2);
        PU u; u.u[0] = a; u.u[1] = c2; u.u[2] = b; u.u[3] = d2;
        pf[g] = u.v;
      }

      // PV: acc[dg] += V^T[dg] . P
      __builtin_amdgcn_s_setprio(1);
#pragma unroll
      for (int g = 0; g < 4; ++g) acc0 = __builtin_amdgcn_mfma_f32_32x32x16_bf16(vf0[g], pf[g], acc0, 0, 0, 0);
#pragma unroll
      for (int g = 0; g < 4; ++g) acc1 = __builtin_amdgcn_mfma_f32_32x32x16_bf16(vf1[g], pf[g], acc1, 0, 0, 0);
      __builtin_amdgcn_s_setprio(0);
    }
  }

  // ---- split-K combine: wave1 -> LDS, wave0 merges + writes y ----
  if (w == 1) {
    if (hi == 0) { lm[0][l31] = mrun; lm[1][l31] = lrun; }
#pragma unroll
    for (int r = 0; r < 16; ++r) {
      int d0 = (r & 3) + 8 * (r >> 2) + 4 * hi;
      lacc[d0][l31] = acc0[r];
      lacc[32 + d0][l31] = acc1[r];
    }
  }
  __syncthreads();
  if (w == 0) {
    float m1 = lm[0][l31], l1 = lm[1][l31];
    float M = fmaxf(mrun, m1);
    float f0 = __builtin_amdgcn_exp2f(mrun - M);
    float f1 = __builtin_amdgcn_exp2f(m1 - M);
    float L = lrun * f0 + l1 * f1;
    float inv = __builtin_amdgcn_rcpf(L);
    const int b = bh >> 2, h = bh & 3;
    __bf16* yrow = yb + (b * SS + q) * CC + h * DD;
#pragma unroll
    for (int g = 0; g < 4; ++g) {
      float a0[4], a1[4];
#pragma unroll
      for (int i2 = 0; i2 < 4; ++i2) {
        int d0 = i2 + 8 * g + 4 * hi;
        a0[i2] = (acc0[g * 4 + i2] * f0 + lacc[d0][l31] * f1) * inv;
        a1[i2] = (acc1[g * 4 + i2] * f0 + lacc[32 + d0][l31] * f1) * inv;
      }
      uint32_t w0 = cvtpk(a0[0], a0[1]);
      uint32_t w1 = cvtpk(a0[2], a0[3]);
      uint2 st0 = { w0, w1 };
      *(uint2*)(yrow + g * 8 + hi * 4) = st0;
      w0 = cvtpk(a1[0], a1[1]);
      w1 = cvtpk(a1[2], a1[3]);
      uint2 st1 = { w0, w1 };
      *(uint2*)(yrow + 32 + g * 8 + hi * 4) = st1;
    }
  }
}

// ---------------- Proj GEMM: out = y @ W_proj^T (fp32 out) ------------------
__global__ __launch_bounds__(256) void proj_gemm(const __bf16* __restrict__ yb,
                                                 const __bf16* __restrict__ wpb,
                                                 float* __restrict__ out) {
  const int lane = threadIdx.x & 63;
  const int ln = lane & 15, kg = lane >> 4;
  const int w = threadIdx.x >> 6;
  const int otile = blockIdx.x & 3;
  const int r0 = (blockIdx.x >> 2) * 256 + w * 64;
  const int o0 = otile * 64;

  f32x4 acc[4][4] = {};
  for (int c0 = 0; c0 < CC; c0 += 32) {
    bf16x8 a[4], wv[4];
#pragma unroll
    for (int i = 0; i < 4; ++i)
      a[i] = *(const bf16x8*)(yb + (r0 + i * 16 + ln) * CC + c0 + kg * 8);
#pragma unroll
    for (int t = 0; t < 4; ++t)
      wv[t] = *(const bf16x8*)(wpb + (o0 + t * 16 + ln) * CC + c0 + kg * 8);
#pragma unroll
    for (int i = 0; i < 4; ++i)
#pragma unroll
      for (int t = 0; t < 4; ++t)
        acc[i][t] = __builtin_amdgcn_mfma_f32_16x16x32_bf16(a[i], wv[t], acc[i][t], 0, 0, 0);
  }
#pragma unroll
  for (int i = 0; i < 4; ++i)
#pragma unroll
    for (int t = 0; t < 4; ++t) {
      int o = o0 + t * 16 + ln;
#pragma unroll
      for (int r = 0; r < 4; ++r) {
        int rout = r0 + i * 16 + kg * 4 + r;
        out[rout * 256 + o] = acc[i][t][r];
      }
    }
}

extern "C" void kernel_launch(void* const* d_in, const int* in_sizes, int n_in,
                              void* d_out, int out_size, void* d_ws, size_t ws_size,
                              hipStream_t stream) {
  const float* x = (const float*)d_in[0];
  const float* Wa = (const float*)d_in[1];
  const float* Wp = (const float*)d_in[2];

  char* ws = (char*)d_ws;
  __bf16* xb  = (__bf16*)(ws);                    // 8 MiB  [B*S][C]
  __bf16* qfb = (__bf16*)(ws + 8388608);          // 8 MiB  Qf fragment layout
  __bf16* kfb = (__bf16*)(ws + 16777216);         // 8 MiB  Kf (pre-scaled)
  __bf16* vfb = (__bf16*)(ws + 25165824);         // 8 MiB  Vf
  __bf16* yb  = (__bf16*)(ws + 33554432);         // 8 MiB  [B,S,C]
  __bf16* wab = (__bf16*)(ws + 41943040);         // 384 KiB [768][256]
  __bf16* wpb = (__bf16*)(ws + 42336256);         // 128 KiB [256][256]

  cvt3_kernel<<<4352, 256, 0, stream>>>(x, Wa, Wp, xb, wab, wpb);
  qkv_gemm<<<768, 256, 0, stream>>>(xb, wab, qfb, kfb, vfb);
  attn_kernel<<<2048, 128, 0, stream>>>(qfb, kfb, vfb, yb);
  proj_gemm<<<256, 256, 0, stream>>>(yb, wpb, (float*)d_out);
}